// Round 1
// baseline (227.313 us; speedup 1.0000x reference)
//
#include <hip/hip_runtime.h>
#include <hip/hip_fp16.h>
#include <stdint.h>
#include <string.h>

#define NV 40962     // vertices
#define NC 64        // in channels
#define NO 64        // out channels
#define NM 27        // neighbors*3
#define NB 4         // batch
#define KP 576       // K = 9*64, permuted t = k*64 + c (k-major)
#define NPAD 28      // padded pairs per vertex (112 B rows, 16B-aligned)

using fragh = __attribute__((ext_vector_type(8))) _Float16;  // 8 f16 (4 VGPRs)
using f32x4 = __attribute__((ext_vector_type(4))) float;     // MFMA acc

__device__ inline __half2 uh2(unsigned int u) { __half2 h; memcpy(&h, &u, 4); return h; }
__device__ inline unsigned int h2u(__half2 h) { unsigned int u; memcpy(&u, &h, 4); return u; }
__device__ inline unsigned short f2h(float f) {
    __half h = __float2half_rn(f);
    unsigned short u; memcpy(&u, &h, 2); return u;
}
__device__ inline unsigned int pack_h2(float a, float b) {
    __half2 h = __floats2half2_rn(a, b);
    unsigned int u; memcpy(&u, &h, 4); return u;
}
__device__ inline unsigned int comp(const uint4& v, int i) {
    switch (i & 3) { case 0: return v.x; case 1: return v.y; case 2: return v.z; default: return v.w; }
}

// ---- prep: W -> Wp f16 (t = k*64+c), and (idx,w) -> packed pairs (f16 w | idx) ----
__global__ __launch_bounds__(256) void prep_kernel(const float* __restrict__ W,
                                                   const int* __restrict__ nidx,
                                                   const float* __restrict__ nwt,
                                                   unsigned short* __restrict__ Wp,
                                                   unsigned int* __restrict__ pairs) {
    int i = blockIdx.x * 256 + threadIdx.x;
    if (i < NO * KP) {
        int o = i / KP, t = i % KP;
        int k = t >> 6, c = t & 63;
        Wp[i] = f2h(W[o * 576 + c * 9 + k]);
    }
    if (i < NV * NPAD) {
        int v = i / NPAD, j = i - v * NPAD;
        unsigned int pv = 0;
        if (j < NM) {
            unsigned int id = (unsigned int)nidx[v * NM + j];   // < 40962, fits 16 bits
            unsigned int wb = (unsigned int)f2h(nwt[v * NM + j]);
            pv = (wb << 16) | (id & 0xffffu);
        }
        pairs[i] = pv;
    }
}

// ---- x (B,C,V) fp32 -> xt (B,V,C) f16 ----
__global__ __launch_bounds__(256) void transpose_kernel(const float* __restrict__ x,
                                                        unsigned short* __restrict__ xt) {
    __shared__ float tile[64][65];
    int b = blockIdx.y;
    int v0 = blockIdx.x * 64;
    int t = threadIdx.x;
    int tv = t & 63, tc = t >> 6;
    const float* xb = x + (size_t)b * NC * NV;
    #pragma unroll
    for (int i = 0; i < 16; i++) {
        int c = tc + i * 4;
        int v = v0 + tv;
        tile[c][tv] = (v < NV) ? xb[(size_t)c * NV + v] : 0.f;
    }
    __syncthreads();
    unsigned short* xtb = xt + (size_t)b * NV * NC;
    #pragma unroll
    for (int i = 0; i < 2; i++) {
        int r = i * 32 + (t >> 3);
        int ch0 = (t & 7) * 8;
        int v = v0 + r;
        if (v < NV) {
            unsigned int o[4];
            #pragma unroll
            for (int j = 0; j < 4; j++)
                o[j] = pack_h2(tile[ch0 + 2 * j][r], tile[ch0 + 2 * j + 1][r]);
            *(uint4*)(xtb + (size_t)v * NC + ch0) = *(const uint4*)o;
        }
    }
}

// ---- fused gather + MFMA GEMM, zero LDS, per-kslot interleave ----
// block = 64 = 1 wave; wave = 16 vertices x 64 outputs x 2 BATCHES.
// lane = (q = lane>>4, m = lane&15). Lane's gathered channels q*8..+7 (lo)
// and 32+q*8..+7 (hi) ARE the A-frag layout for k-steps 2k / 2k+1.
// f16 path: gathered uint4 is directly v_pk_fma_f16-consumable (no unpack),
// and the half2 accumulators ARE the MFMA A-frag (no repack).
// Per k-slot: 12 gathers (2 batches x 3 neighbors x 2 halves), 48 pk_fma_f16,
// 16 MFMAs. 1-slot gather lookahead; C stays in AGPRs.
__global__ __launch_bounds__(64, 2) void fused_kernel(
    const unsigned short* __restrict__ xt,
    const unsigned int* __restrict__ pairs,
    const unsigned short* __restrict__ Wp,
    const float* __restrict__ bias,
    float* __restrict__ out)
{
    int lane = threadIdx.x;
    int q = lane >> 4;          // channel quad
    int m = lane & 15;          // vertex within tile
    int bp = blockIdx.y;        // batch pair: batches 2bp, 2bp+1
    int n0 = blockIdx.x * 16;
    int vtx = n0 + m; if (vtx >= NV) vtx = NV - 1;
    const char* xb0 = (const char*)xt + (size_t)(2 * bp) * NV * NC * 2;
    const char* xb1 = xb0 + (size_t)NV * NC * 2;
    int cofs = q * 16;

    // all 27 (idx | f16 w) pairs for this lane's vertex
    uint4 pr[7];
    {
        const uint4* pp = (const uint4*)(pairs + (size_t)vtx * NPAD);
        #pragma unroll
        for (int j = 0; j < 7; j++) pr[j] = pp[j];
    }

    f32x4 c[2][4];
    #pragma unroll
    for (int bb = 0; bb < 2; bb++)
        #pragma unroll
        for (int j = 0; j < 4; j++) c[bb][j] = (f32x4){0.f, 0.f, 0.f, 0.f};

    uint4 ga[2][2][3], gb[2][2][3];  // [buf][batch][neighbor]

    // prologue: issue k-slot 0 gathers
    #pragma unroll
    for (int j = 0; j < 3; j++) {
        unsigned int pm = comp(pr[0], j);
        unsigned int off = ((pm & 0xffffu) << 7) + cofs;
        ga[0][0][j] = *(const uint4*)(xb0 + off);
        gb[0][0][j] = *(const uint4*)(xb0 + off + 64);
        ga[0][1][j] = *(const uint4*)(xb1 + off);
        gb[0][1][j] = *(const uint4*)(xb1 + off + 64);
    }

    const unsigned short* wrow = Wp + q * 8;

    #pragma unroll
    for (int k = 0; k < 9; k++) {
        int cur = k & 1, nxt = cur ^ 1;
        // lookahead: issue k+1's 12 gathers before consuming k's
        if (k < 8) {
            #pragma unroll
            for (int j = 0; j < 3; j++) {
                int mm = 3 * (k + 1) + j;
                unsigned int pm = comp(pr[mm >> 2], mm);
                unsigned int off = ((pm & 0xffffu) << 7) + cofs;
                ga[nxt][0][j] = *(const uint4*)(xb0 + off);
                gb[nxt][0][j] = *(const uint4*)(xb0 + off + 64);
                ga[nxt][1][j] = *(const uint4*)(xb1 + off);
                gb[nxt][1][j] = *(const uint4*)(xb1 + off + 64);
            }
        }
        // accumulate k's 3 neighbors, 16 channels x 2 batches — packed f16 fma
        unsigned int accA[2][4], accB[2][4];
        #pragma unroll
        for (int bb = 0; bb < 2; bb++)
            #pragma unroll
            for (int d = 0; d < 4; d++) { accA[bb][d] = 0u; accB[bb][d] = 0u; }
        #pragma unroll
        for (int j = 0; j < 3; j++) {
            int mm = 3 * k + j;
            unsigned int pm = comp(pr[mm >> 2], mm);
            unsigned int wh = pm >> 16;
            __half2 w2 = uh2((wh << 16) | wh);
            #pragma unroll
            for (int bb = 0; bb < 2; bb++) {
                uint4 u0 = bb ? ga[cur][1][j] : ga[cur][0][j];
                uint4 u1 = bb ? gb[cur][1][j] : gb[cur][0][j];
                const unsigned int d0[4] = {u0.x, u0.y, u0.z, u0.w};
                const unsigned int d1[4] = {u1.x, u1.y, u1.z, u1.w};
                #pragma unroll
                for (int d = 0; d < 4; d++) {
                    accA[bb][d] = h2u(__hfma2(uh2(d0[d]), w2, uh2(accA[bb][d])));
                    accB[bb][d] = h2u(__hfma2(uh2(d1[d]), w2, uh2(accB[bb][d])));
                }
            }
        }
        // acc registers ARE the A-frags; run k-steps 2k (lo) and 2k+1 (hi)
        fragh a0[2], a1[2];
        #pragma unroll
        for (int bb = 0; bb < 2; bb++) {
            memcpy(&a0[bb], accA[bb], 16);
            memcpy(&a1[bb], accB[bb], 16);
        }
        #pragma unroll
        for (int j = 0; j < 4; j++) {
            fragh blo = *(const fragh*)(wrow + (size_t)(j * 16 + m) * KP + (2 * k) * 32);
            fragh bhi = *(const fragh*)(wrow + (size_t)(j * 16 + m) * KP + (2 * k + 1) * 32);
            c[0][j] = __builtin_amdgcn_mfma_f32_16x16x32_f16(a0[0], blo, c[0][j], 0, 0, 0);
            c[0][j] = __builtin_amdgcn_mfma_f32_16x16x32_f16(a1[0], bhi, c[0][j], 0, 0, 0);
            c[1][j] = __builtin_amdgcn_mfma_f32_16x16x32_f16(a0[1], blo, c[1][j], 0, 0, 0);
            c[1][j] = __builtin_amdgcn_mfma_f32_16x16x32_f16(a1[1], bhi, c[1][j], 0, 0, 0);
        }
    }

    // epilogue: D[row = q*4+i (vertex)][col = m+16j (out)], + bias, float2 stores
    int nbase = n0 + q * 4;
    #pragma unroll
    for (int bb = 0; bb < 2; bb++) {
        size_t outb = (size_t)(2 * bp + bb) * NO * NV;
        #pragma unroll
        for (int j = 0; j < 4; j++) {
            int o = j * 16 + m;
            float bo = bias[o];
            f32x4 vv = c[bb][j];
            float* op = out + outb + (size_t)o * NV + nbase;
            if (nbase + 4 <= NV) {
                *(float2*)op       = make_float2(vv[0] + bo, vv[1] + bo);
                *(float2*)(op + 2) = make_float2(vv[2] + bo, vv[3] + bo);
            } else {
                #pragma unroll
                for (int i = 0; i < 4; i++)
                    if (nbase + i < NV) op[i] = vv[i] + bo;
            }
        }
    }
}

extern "C" void kernel_launch(void* const* d_in, const int* in_sizes, int n_in,
                              void* d_out, int out_size, void* d_ws, size_t ws_size,
                              hipStream_t stream) {
    const float* x    = (const float*)d_in[0];  // (4,64,40962) fp32
    const int*   nidx = (const int*)d_in[1];    // (40962,27) int32
    const float* nwt  = (const float*)d_in[2];  // (40962,27) fp32
    const float* W    = (const float*)d_in[3];  // (64,576) fp32
    const float* bias = (const float*)d_in[4];  // (64,) fp32
    float* out = (float*)d_out;                 // (4,64,40962) fp32

    unsigned short* Wp    = (unsigned short*)d_ws;                       // 72 KB
    unsigned short* xt    = (unsigned short*)((char*)d_ws + 131072);     // 21 MB
    unsigned int*   pairs = (unsigned int*)((char*)d_ws + 131072 + (size_t)NB * NV * NC * 2);  // 4.6 MB

    prep_kernel<<<dim3((NV * NPAD + 255) / 256), 256, 0, stream>>>(W, nidx, nwt, Wp, pairs);
    transpose_kernel<<<dim3((NV + 63) / 64, NB), 256, 0, stream>>>(x, xt);
    fused_kernel<<<dim3((NV + 15) / 16, NB / 2), 64, 0, stream>>>(xt, pairs, Wp, bias, out);
}